// Round 18
// baseline (882.322 us; speedup 1.0000x reference)
//
#include <hip/hip_runtime.h>
#include <math.h>

#define EPS_F 1e-6f
#define ONE_M_EPS (1.0f - 1e-6f)

typedef __attribute__((ext_vector_type(8))) short s16x8;
typedef __attribute__((ext_vector_type(8))) _Float16 f16x8;
typedef __attribute__((ext_vector_type(4))) float f32x4;

__device__ __forceinline__ ushort f2bf(float f) {
    union { float f; unsigned u; } v; v.f = f;
    unsigned u = v.u;
    return (ushort)((u + 0x7FFFu + ((u >> 16) & 1u)) >> 16);
}
__device__ __forceinline__ float bf2f(ushort h) {
    union { unsigned u; float f; } v; v.u = ((unsigned)h) << 16;
    return v.f;
}
// fp16 2-plane split: x = h + m, |x - h - m| <= 2^-22 |x|
__device__ __forceinline__ void split2h(float x, ushort& h, ushort& m) {
    union { _Float16 f; ushort u; } a, b;
    a.f = (_Float16)x;
    float r = x - (float)a.f;
    b.f = (_Float16)r;
    h = a.u; m = b.u;
}

#define GLL16(srcp, dstp)                                                     \
    __builtin_amdgcn_global_load_lds(                                         \
        (const __attribute__((address_space(1))) void*)(srcp),                \
        (__attribute__((address_space(3))) void*)(dstp), 16, 0, 0)

// Bank-conflict swizzle (16B-chunk granularity; source+read, LDS linear)
__device__ __forceinline__ int swz_k(int row, int k) { return k ^ ((row >> 1) & 3); }

// Block remap: XCD chunking (bijective, nwg%8==0) + 2x2 supertile clustering
__device__ __forceinline__ void tile_remap(int MB, int NB, int& bm_i, int& bn_i) {
    const int lin = blockIdx.y * MB + blockIdx.x;
    const int nwg = MB * NB;
    int wg = lin;
    if ((nwg & 7) == 0)
        wg = (lin & 7) * (nwg >> 3) + (lin >> 3);
    if (((MB | NB) & 1) == 0) {
        const int tiles_m = MB >> 1;
        const int stile = wg >> 2, within = wg & 3;
        const int st_m = stile % tiles_m, st_n = stile / tiles_m;
        bm_i = st_m * 2 + (within & 1);
        bn_i = st_n * 2 + (within >> 1);
    } else {
        bm_i = wg % MB;
        bn_i = wg / MB;
    }
}

// ---------------------------------------------------------------------------
// 2-plane fp16 MFMA GEMM (encoder): 3 products (hh,hm,mh), fp32 acc.
// 2-phase double-buffered pipeline, counted vmcnt(8), remapped blocks.
// ---------------------------------------------------------------------------
template<bool RELU, int OUT2>
__global__ __launch_bounds__(256) void gemm_mfma_split2(
    const ushort* __restrict__ Ah, const ushort* __restrict__ Am,
    const ushort* __restrict__ Wh, const ushort* __restrict__ Wm,
    const float* __restrict__ bias,
    void* __restrict__ C0, void* __restrict__ C1,
    int M, int N, int K)
{
    __shared__ __align__(16) ushort As[2][2][128 * 32];   // [dbuf][plane]
    __shared__ __align__(16) ushort Bs[2][2][128 * 32];

    const int tid  = threadIdx.x;
    const int lane = tid & 63;
    const int w    = tid >> 6;
    const int wm   = (w >> 1) * 64;
    const int wn   = (w & 1) * 64;
    int bmi, bni;
    tile_remap(gridDim.x, gridDim.y, bmi, bni);
    const int bm   = bmi * 128;
    const int bn   = bni * 128;

    f32x4 acc[4][4];
#pragma unroll
    for (int i = 0; i < 4; i++)
#pragma unroll
        for (int j = 0; j < 4; j++) acc[i][j] = f32x4{0.f, 0.f, 0.f, 0.f};

    const int c0 = (w * 2) * 64 + lane;
    const int c1 = (w * 2 + 1) * 64 + lane;
    const int r0 = c0 >> 2, k0e = swz_k(r0, c0 & 3) * 8;
    const int r1 = c1 >> 2, k1e = swz_k(r1, c1 & 3) * 8;

    const size_t a_off0 = (size_t)(bm + r0) * K + k0e;
    const size_t a_off1 = (size_t)(bm + r1) * K + k1e;
    const size_t b_off0 = (size_t)(bn + r0) * K + k0e;
    const size_t b_off1 = (size_t)(bn + r1) * K + k1e;
    const int d0 = (w * 2) * 512;
    const int d1 = d0 + 512;

    const ushort* Ap[2] = {Ah, Am};
    const ushort* Wp[2] = {Wh, Wm};

    const int fm  = lane & 15;
    const int fkb = lane >> 4;
    const int NT  = K >> 5;

    // prologue: stage tile 0 -> buf 0
#pragma unroll
    for (int p = 0; p < 2; p++) {
        GLL16(Ap[p] + a_off0, &As[0][p][d0]);
        GLL16(Ap[p] + a_off1, &As[0][p][d1]);
        GLL16(Wp[p] + b_off0, &Bs[0][p][d0]);
        GLL16(Wp[p] + b_off1, &Bs[0][p][d1]);
    }

    int cur = 0;
    for (int kt = 0; kt < NT; kt++) {
        if (kt + 1 < NT) {
            const int kk = (kt + 1) << 5;
#pragma unroll
            for (int p = 0; p < 2; p++) {
                GLL16(Ap[p] + a_off0 + kk, &As[cur ^ 1][p][d0]);
                GLL16(Ap[p] + a_off1 + kk, &As[cur ^ 1][p][d1]);
                GLL16(Wp[p] + b_off0 + kk, &Bs[cur ^ 1][p][d0]);
                GLL16(Wp[p] + b_off1 + kk, &Bs[cur ^ 1][p][d1]);
            }
            asm volatile("s_waitcnt vmcnt(8)" ::: "memory");  // tile t complete
        } else {
            asm volatile("s_waitcnt vmcnt(0)" ::: "memory");
        }
        __builtin_amdgcn_s_barrier();
        asm volatile("" ::: "memory");

        f16x8 af[2][4];
#pragma unroll
        for (int p = 0; p < 2; p++)
#pragma unroll
            for (int i = 0; i < 4; i++) {
                const int row = wm + i * 16 + fm;
                af[p][i] = *reinterpret_cast<const f16x8*>(
                    &As[cur][p][row * 32 + swz_k(row, fkb) * 8]);
            }
        f16x8 bf0[4], bf1[4];
#pragma unroll
        for (int j = 0; j < 4; j++) {
            const int row = wn + j * 16 + fm;
            bf0[j] = *reinterpret_cast<const f16x8*>(&Bs[cur][0][row * 32 + swz_k(row, fkb) * 8]);
            bf1[j] = *reinterpret_cast<const f16x8*>(&Bs[cur][1][row * 32 + swz_k(row, fkb) * 8]);
        }

        __builtin_amdgcn_s_setprio(1);
#pragma unroll
        for (int i = 0; i < 4; i++)
#pragma unroll
            for (int j = 0; j < 4; j++) {
                acc[i][j] = __builtin_amdgcn_mfma_f32_16x16x32_f16(af[0][i], bf0[j], acc[i][j], 0, 0, 0);
                acc[i][j] = __builtin_amdgcn_mfma_f32_16x16x32_f16(af[0][i], bf1[j], acc[i][j], 0, 0, 0);
                acc[i][j] = __builtin_amdgcn_mfma_f32_16x16x32_f16(af[1][i], bf0[j], acc[i][j], 0, 0, 0);
            }
        __builtin_amdgcn_s_setprio(0);
        asm volatile("" ::: "memory");
        __builtin_amdgcn_s_barrier();   // reads of buf[cur] done before t+1 overwrites it
        cur ^= 1;
    }

#pragma unroll
    for (int j = 0; j < 4; j++) {
        const int coln = bn + wn + j * 16 + fm;
        const float bv = bias[coln];
#pragma unroll
        for (int i = 0; i < 4; i++) {
            const int row0 = bm + wm + i * 16 + (lane >> 4) * 4;
#pragma unroll
            for (int r = 0; r < 4; r++) {
                float o = acc[i][j][r] + bv;
                if (RELU) o = fmaxf(o, 0.f);
                const size_t idx = (size_t)(row0 + r) * N + coln;
                if (OUT2) {
                    ushort h, m;
                    split2h(o, h, m);
                    ((ushort*)C0)[idx] = h;
                    ((ushort*)C1)[idx] = m;
                } else {
                    ((float*)C0)[idx] = o;
                }
            }
        }
    }
}

// ---------------------------------------------------------------------------
// MFMA bf16 GEMM (decoder, single product), 2-phase pipelined, remapped
// ---------------------------------------------------------------------------
template<bool RELU, bool OUT_BF16>
__global__ __launch_bounds__(256) void gemm_mfma_bt(
    const ushort* __restrict__ A, const ushort* __restrict__ WT,
    const float* __restrict__ bias, void* __restrict__ Cv,
    int M, int N, int K)
{
    __shared__ __align__(16) ushort As[2][128 * 32];
    __shared__ __align__(16) ushort Bs[2][128 * 32];

    const int tid  = threadIdx.x;
    const int lane = tid & 63;
    const int w    = tid >> 6;
    const int wm   = (w >> 1) * 64;
    const int wn   = (w & 1) * 64;
    int bmi, bni;
    tile_remap(gridDim.x, gridDim.y, bmi, bni);
    const int bm   = bmi * 128;
    const int bn   = bni * 128;

    f32x4 acc[4][4];
#pragma unroll
    for (int i = 0; i < 4; i++)
#pragma unroll
        for (int j = 0; j < 4; j++) acc[i][j] = f32x4{0.f, 0.f, 0.f, 0.f};

    const int c0 = (w * 2) * 64 + lane;
    const int c1 = (w * 2 + 1) * 64 + lane;
    const int r0 = c0 >> 2, k0e = swz_k(r0, c0 & 3) * 8;
    const int r1 = c1 >> 2, k1e = swz_k(r1, c1 & 3) * 8;

    const ushort* a_src0 = A  + (size_t)(bm + r0) * K + k0e;
    const ushort* a_src1 = A  + (size_t)(bm + r1) * K + k1e;
    const ushort* b_src0 = WT + (size_t)(bn + r0) * K + k0e;
    const ushort* b_src1 = WT + (size_t)(bn + r1) * K + k1e;
    const int d0 = (w * 2) * 512;
    const int d1 = d0 + 512;

    const int fm  = lane & 15;
    const int fkb = lane >> 4;
    const int NT  = K >> 5;

    GLL16(a_src0, &As[0][d0]);
    GLL16(a_src1, &As[0][d1]);
    GLL16(b_src0, &Bs[0][d0]);
    GLL16(b_src1, &Bs[0][d1]);

    int cur = 0;
    for (int kt = 0; kt < NT; kt++) {
        if (kt + 1 < NT) {
            const int kk = (kt + 1) << 5;
            GLL16(a_src0 + kk, &As[cur ^ 1][d0]);
            GLL16(a_src1 + kk, &As[cur ^ 1][d1]);
            GLL16(b_src0 + kk, &Bs[cur ^ 1][d0]);
            GLL16(b_src1 + kk, &Bs[cur ^ 1][d1]);
            asm volatile("s_waitcnt vmcnt(4)" ::: "memory");
        } else {
            asm volatile("s_waitcnt vmcnt(0)" ::: "memory");
        }
        __builtin_amdgcn_s_barrier();
        asm volatile("" ::: "memory");

        s16x8 af[4], bfr[4];
#pragma unroll
        for (int i = 0; i < 4; i++) {
            const int row = wm + i * 16 + fm;
            af[i] = *reinterpret_cast<const s16x8*>(&As[cur][row * 32 + swz_k(row, fkb) * 8]);
        }
#pragma unroll
        for (int j = 0; j < 4; j++) {
            const int row = wn + j * 16 + fm;
            bfr[j] = *reinterpret_cast<const s16x8*>(&Bs[cur][row * 32 + swz_k(row, fkb) * 8]);
        }

        __builtin_amdgcn_s_setprio(1);
#pragma unroll
        for (int i = 0; i < 4; i++)
#pragma unroll
            for (int j = 0; j < 4; j++)
                acc[i][j] = __builtin_amdgcn_mfma_f32_16x16x32_bf16(
                    af[i], bfr[j], acc[i][j], 0, 0, 0);
        __builtin_amdgcn_s_setprio(0);
        asm volatile("" ::: "memory");
        __builtin_amdgcn_s_barrier();
        cur ^= 1;
    }

#pragma unroll
    for (int j = 0; j < 4; j++) {
        const int coln = bn + wn + j * 16 + fm;
        const float bv = bias[coln];
#pragma unroll
        for (int i = 0; i < 4; i++) {
            const int row0 = bm + wm + i * 16 + (lane >> 4) * 4;
#pragma unroll
            for (int r = 0; r < 4; r++) {
                float o = acc[i][j][r] + bv;
                if (RELU) o = fmaxf(o, 0.f);
                if (OUT_BF16)
                    ((ushort*)Cv)[(size_t)(row0 + r) * N + coln] = f2bf(o);
                else
                    ((float*)Cv)[(size_t)(row0 + r) * N + coln] = o;
            }
        }
    }
}

// ---------------------------------------------------------------------------
// Weight prep kernels
// ---------------------------------------------------------------------------
__global__ __launch_bounds__(256) void transpose_to_bf16(
    const float* __restrict__ W, ushort* __restrict__ WT, int K, int N)
{
    __shared__ float t[32][33];
    const int kb = blockIdx.x * 32, nb = blockIdx.y * 32;
    const int tx = threadIdx.x & 31, ty = threadIdx.x >> 5;
#pragma unroll
    for (int i = ty; i < 32; i += 8)
        t[i][tx] = W[(size_t)(kb + i) * N + nb + tx];
    __syncthreads();
#pragma unroll
    for (int i = ty; i < 32; i += 8)
        WT[(size_t)(nb + i) * K + kb + tx] = f2bf(t[tx][i]);
}

__global__ __launch_bounds__(256) void transpose_split_f16(
    const float* __restrict__ W, ushort* __restrict__ TH,
    ushort* __restrict__ TM, int K, int N)
{
    __shared__ float t[32][33];
    const int kb = blockIdx.x * 32, nb = blockIdx.y * 32;
    const int tx = threadIdx.x & 31, ty = threadIdx.x >> 5;
#pragma unroll
    for (int i = ty; i < 32; i += 8)
        t[i][tx] = W[(size_t)(kb + i) * N + nb + tx];
    __syncthreads();
#pragma unroll
    for (int i = ty; i < 32; i += 8) {
        ushort h, m;
        split2h(t[tx][i], h, m);
        const size_t idx = (size_t)(nb + i) * K + kb + tx;
        TH[idx] = h; TM[idx] = m;
    }
}

// vectorized: 4 floats in, ushort4 out per thread
__global__ __launch_bounds__(256) void split_plane2v_kernel(
    const float4* __restrict__ X, ushort* __restrict__ H,
    ushort* __restrict__ M, size_t n4)
{
    size_t i = (size_t)blockIdx.x * 256 + threadIdx.x;
    if (i >= n4) return;
    float4 v = X[i];
    union { ushort u[4]; unsigned long long ll; } h, m;
    split2h(v.x, h.u[0], m.u[0]);
    split2h(v.y, h.u[1], m.u[1]);
    split2h(v.z, h.u[2], m.u[2]);
    split2h(v.w, h.u[3], m.u[3]);
    *reinterpret_cast<unsigned long long*>(&H[i * 4]) = h.ll;
    *reinterpret_cast<unsigned long long*>(&M[i * 4]) = m.ll;
}

// ---------------------------------------------------------------------------
// Codebook prep
// ---------------------------------------------------------------------------
__global__ __launch_bounds__(128) void prep_cb_kernel(
    const float* __restrict__ cb, float* __restrict__ cbT, float* __restrict__ cnorm)
{
    int b = blockIdx.x;
    int d = threadIdx.x;
    float v = cb[(size_t)b * 128 + d];
    int l = b >> 8, c = b & 255;
    cbT[((size_t)l * 128 + d) * 256 + c] = v;
    float s = v * v;
#pragma unroll
    for (int off = 32; off > 0; off >>= 1) s += __shfl_down(s, off);
    __shared__ float ps[2];
    if ((d & 63) == 0) ps[d >> 6] = s;
    __syncthreads();
    if (d == 0) cnorm[b] = ps[0] + ps[1];
}

__device__ __forceinline__ float softplusf(float x) {
    return (x > 20.f) ? x : log1pf(expf(x));
}

__global__ void kuma_ab_init(const float* __restrict__ a_raw, const float* __restrict__ b_raw,
                             float* __restrict__ kp)
{
    int t = threadIdx.x;
    if (t < 128) {
        float a = softplusf(a_raw[t]) + EPS_F;
        float b = softplusf(b_raw[t]) + EPS_F;
        kp[t] = a;
        kp[128 + t] = b;
        kp[256 + t] = 1.f / a;
        kp[384 + t] = 1.f / b;
    }
}

__global__ __launch_bounds__(256) void kuma_h_kernel(
    const float* __restrict__ z, const float* __restrict__ kp,
    float* __restrict__ zp, int n)
{
    int i = blockIdx.x * 256 + threadIdx.x;
    if (i >= n) return;
    int col = i & 127;
    float a = kp[col], b = kp[128 + col];
    float zv = z[i];
    float x = 1.f / (1.f + expf(-zv));
    x = fminf(fmaxf(x, EPS_F), ONE_M_EPS);
    float inner = 1.f - powf(x, a);
    inner = fminf(fmaxf(inner, EPS_F), 1.f);
    float y = 1.f - powf(inner, b);
    y = fminf(fmaxf(y, EPS_F), ONE_M_EPS);
    zp[i] = y;
}

// ---------------------------------------------------------------------------
// Residual quantizer v4 — 1 wave/block, 16 rows, 4 codes/thread.
// Quarters cbT L2 traffic vs the 4-row version.
// ---------------------------------------------------------------------------
__global__ __launch_bounds__(64) void rq_kernel4(
    const float* __restrict__ zp, const float* __restrict__ cb,
    const float* __restrict__ cbT, const float* __restrict__ cnorm,
    float* __restrict__ xq, float* __restrict__ idx_out,
    float* __restrict__ prq, int bid0, int nRq)
{
    __shared__ float res[16][128];

    const int t = threadIdx.x;
    const int row0 = blockIdx.x * 16;

#pragma unroll
    for (int j = 0; j < 32; j++) {
        int e = t + j * 64;
        res[e >> 7][e & 127] = zp[(size_t)row0 * 128 + e];
    }

    float lsum[4];
    int bidx[16];

#pragma unroll 1
    for (int l = 0; l < 4; l++) {
        const float* cT = cbT + (size_t)l * 32768;

        float acc[16][4];
#pragma unroll
        for (int r = 0; r < 16; r++)
#pragma unroll
            for (int cc = 0; cc < 4; cc++) acc[r][cc] = 0.f;

        float pc[16];
#pragma unroll
        for (int dd = 0; dd < 4; dd++)
#pragma unroll
            for (int cc = 0; cc < 4; cc++)
                pc[dd * 4 + cc] = cT[dd * 256 + cc * 64 + t];

#pragma unroll 2
        for (int d = 0; d < 128; d += 4) {
            float nc[16];
            if (d < 124) {
#pragma unroll
                for (int dd = 0; dd < 4; dd++)
#pragma unroll
                    for (int cc = 0; cc < 4; cc++)
                        nc[dd * 4 + cc] = cT[(d + 4 + dd) * 256 + cc * 64 + t];
            }
#pragma unroll
            for (int r = 0; r < 16; r++) {
                float4 rv = *reinterpret_cast<const float4*>(&res[r][d]);
#pragma unroll
                for (int cc = 0; cc < 4; cc++) {
                    acc[r][cc] += rv.x * pc[cc] + rv.y * pc[4 + cc]
                                + rv.z * pc[8 + cc] + rv.w * pc[12 + cc];
                }
            }
#pragma unroll
            for (int k = 0; k < 16; k++) pc[k] = nc[k];
        }

        float cn[4];
#pragma unroll
        for (int cc = 0; cc < 4; cc++) cn[cc] = cnorm[l * 256 + cc * 64 + t];

#pragma unroll
        for (int r = 0; r < 16; r++) {
            float dmin = cn[0] - 2.f * acc[r][0];
            int imin = t;
#pragma unroll
            for (int cc = 1; cc < 4; cc++) {
                float dv = cn[cc] - 2.f * acc[r][cc];
                if (dv < dmin) { dmin = dv; imin = cc * 64 + t; }
            }
#pragma unroll
            for (int off = 1; off < 64; off <<= 1) {
                float d2 = __shfl_xor(dmin, off);
                int i2 = __shfl_xor(imin, off);
                if (d2 < dmin || (d2 == dmin && i2 < imin)) { dmin = d2; imin = i2; }
            }
            bidx[r] = imin;
            if (t == 0) idx_out[(size_t)(row0 + r) * 4 + l] = (float)imin;
        }

        float s = 0.f;
#pragma unroll
        for (int j = 0; j < 32; j++) {
            const int r = j >> 1;
            const int d = (j & 1) * 64 + t;
            float q = cb[((size_t)(l * 256) + bidx[r]) * 128 + d];
            float nr = res[r][d] - q;
            res[r][d] = nr;
            s += nr * nr;
        }
        lsum[l] = s;
    }

#pragma unroll
    for (int j = 0; j < 32; j++) {
        int e = t + j * 64;
        xq[(size_t)row0 * 128 + e] = zp[(size_t)row0 * 128 + e] - res[e >> 7][e & 127];
    }

#pragma unroll
    for (int l = 0; l < 4; l++) {
        float s = lsum[l];
#pragma unroll
        for (int off = 32; off > 0; off >>= 1) s += __shfl_down(s, off);
        if (t == 0) prq[(size_t)l * nRq + bid0 + blockIdx.x] = s;
    }
}

// ---------------------------------------------------------------------------
// z_q = h_inv(x_q) (bf16 out);  z_recon = h_inv(z');  nvq partial store.
// Fast transcendentals: outputs are bf16-rounded / loose-tolerance only —
// index path (kuma_h -> rq) keeps precise powf.
// ---------------------------------------------------------------------------
__device__ __forceinline__ float kuma_h_inv_fast(float y, float ia, float ib) {
    y = fminf(fmaxf(y, EPS_F), ONE_M_EPS);
    float omy = fminf(fmaxf(1.f - y, EPS_F), 1.f);
    float p1 = __expf(ib * __logf(omy));
    float inner = fminf(fmaxf(1.f - p1, EPS_F), ONE_M_EPS);
    float x = fminf(fmaxf(__expf(ia * __logf(inner)), EPS_F), ONE_M_EPS);
    return __logf(x / (1.f - x));
}
__device__ __forceinline__ float kuma_h_inv_f(float y, float ia, float ib) {
    y = fminf(fmaxf(y, EPS_F), ONE_M_EPS);
    float omy = fminf(fmaxf(1.f - y, EPS_F), 1.f);
    float inner = fminf(fmaxf(1.f - powf(omy, ib), EPS_F), ONE_M_EPS);
    float x = fminf(fmaxf(powf(inner, ia), EPS_F), ONE_M_EPS);
    return logf(x / (1.f - x));
}

__global__ __launch_bounds__(256) void zq_nvq_kernel(
    const float* __restrict__ xq, const float* __restrict__ zp,
    const float* __restrict__ z, const float* __restrict__ kp,
    float* __restrict__ zq, ushort* __restrict__ zq16,
    float* __restrict__ pnvq, int bid0, int n)
{
    int i = blockIdx.x * 256 + threadIdx.x;
    float ds = 0.f;
    if (i < n) {
        int col = i & 127;
        float ia = kp[256 + col], ib = kp[384 + col];
        float xv = xq[i];
        float zpv = zp[i];
        float zv = z[i];
        float zr = kuma_h_inv_fast(zpv, ia, ib);
        float d = zr - zv;
        ds = d * d;
        float zqv = kuma_h_inv_fast(xv, ia, ib);
        zq[i] = zqv;
        zq16[i] = f2bf(zqv);
    }
#pragma unroll
    for (int off = 32; off > 0; off >>= 1) ds += __shfl_down(ds, off);
    __shared__ float ps[4];
    if ((threadIdx.x & 63) == 0) ps[threadIdx.x >> 6] = ds;
    __syncthreads();
    if (threadIdx.x == 0)
        pnvq[bid0 + blockIdx.x] = ps[0] + ps[1] + ps[2] + ps[3];
}

// ---------------------------------------------------------------------------
// Final loss
// ---------------------------------------------------------------------------
__global__ __launch_bounds__(256) void finalize_kernel(
    const float* __restrict__ prq, const float* __restrict__ pnvq,
    int nRqAll, int nNvq, float* __restrict__ out_loss)
{
    const int t = threadIdx.x;
    float srq = 0.f, snvq = 0.f;
    for (int i = t; i < nRqAll; i += 256) srq += prq[i];
    for (int i = t; i < nNvq; i += 256) snvq += pnvq[i];
#pragma unroll
    for (int off = 32; off > 0; off >>= 1) {
        srq += __shfl_down(srq, off);
        snvq += __shfl_down(snvq, off);
    }
    __shared__ float pr[4], pn[4];
    if ((t & 63) == 0) { pr[t >> 6] = srq; pn[t >> 6] = snvq; }
    __syncthreads();
    if (t == 0) {
        const float inv = 1.f / (16384.f * 128.f);
        float rq = (pr[0] + pr[1] + pr[2] + pr[3]);
        float nv = (pn[0] + pn[1] + pn[2] + pn[3]);
        out_loss[0] = 0.3125f * rq * inv + nv * inv;
    }
}

// ---------------------------------------------------------------------------
// Launcher — fp16 2-plane pipelined MFMA encoder + bf16 pipelined decoder.
// ---------------------------------------------------------------------------
extern "C" void kernel_launch(void* const* d_in, const int* in_sizes, int n_in,
                              void* d_out, int out_size, void* d_ws, size_t ws_size,
                              hipStream_t stream)
{
    constexpr int B = 16384;

    const float* x = (const float*)d_in[0];
    const float* enc_w[4]; const float* enc_b[4];
    const float* dec_w[4]; const float* dec_b[4];
    for (int i = 0; i < 4; i++) {
        enc_w[i] = (const float*)d_in[1 + 4 * i];
        enc_b[i] = (const float*)d_in[2 + 4 * i];
        dec_w[i] = (const float*)d_in[3 + 4 * i];
        dec_b[i] = (const float*)d_in[4 + 4 * i];
    }
    const float* cb    = (const float*)d_in[17];
    const float* a_raw = (const float*)d_in[18];
    const float* b_raw = (const float*)d_in[19];

    // chunk size
    size_t avail = ws_size / 4;
    const size_t fixed_f = 6547008;
    int R = 16384;
    while (R > 256 && (size_t)R * 3520 + fixed_f > avail) R >>= 1;

    // carve (floats)
    float* ws    = (float*)d_ws;
    float* slotA = ws;                         // R*1024 fl
    float* slotB = slotA + (size_t)R * 1024;   // R*2048 fl
    float* zb    = slotB + (size_t)R * 2048;   // R*128
    float* zpb   = zb  + (size_t)R * 128;      // R*128
    float* xqb   = zpb + (size_t)R * 128;      // R*128
    float* zq16f = xqb + (size_t)R * 128;      // R*64 (ushort R*128)
    float* fixp  = zq16f + (size_t)R * 64;

    ushort* ew = (ushort*)fixp;
    ushort* e0h = ew;            ushort* e0m = e0h + 1572864;
    ushort* e1h = e0m + 1572864; ushort* e1m = e1h + 2097152;
    ushort* e2h = e1m + 2097152; ushort* e2m = e2h + 524288;
    ushort* e3h = e2m + 524288;  ushort* e3m = e3h + 65536;
    ushort* wt0 = e3m + 65536;
    ushort* wt1 = wt0 + 65536;
    ushort* wt2 = wt1 + 524288;
    ushort* wt3 = wt2 + 2097152;
    float* cbT   = (float*)(wt3 + 1572864);
    float* cnorm = cbT + 4 * 128 * 256;
    float* kp    = cnorm + 4 * 256;
    float* prq   = kp + 512;              // 4 * (B/16) = 4096
    float* pnvq  = prq + 16384;           // 8192

    ushort* zq16 = (ushort*)zq16f;

    ushort* xH  = (ushort*)slotA;  ushort* xM  = xH  + (size_t)R * 768;
    ushort* h0H = (ushort*)slotB;  ushort* h0M = h0H + (size_t)R * 2048;
    ushort* h1H = (ushort*)slotA;  ushort* h1M = h1H + (size_t)R * 1024;
    ushort* h2H = (ushort*)slotB;  ushort* h2M = h2H + (size_t)R * 512;

    ushort* dA = (ushort*)slotB;
    ushort* dB = (ushort*)(slotB + (size_t)R * 256);
    ushort* dC = (ushort*)slotA;

    float* out      = (float*)d_out;
    float* out_loss = out + (size_t)B * 768;
    float* out_idx  = out_loss + 1;

    // prep (once per launch)
    prep_cb_kernel<<<1024, 128, 0, stream>>>(cb, cbT, cnorm);
    kuma_ab_init<<<1, 128, 0, stream>>>(a_raw, b_raw, kp);
    transpose_split_f16<<<dim3( 768/32, 2048/32), 256, 0, stream>>>(enc_w[0], e0h, e0m,  768, 2048);
    transpose_split_f16<<<dim3(2048/32, 1024/32), 256, 0, stream>>>(enc_w[1], e1h, e1m, 2048, 1024);
    transpose_split_f16<<<dim3(1024/32,  512/32), 256, 0, stream>>>(enc_w[2], e2h, e2m, 1024,  512);
    transpose_split_f16<<<dim3( 512/32,  128/32), 256, 0, stream>>>(enc_w[3], e3h, e3m,  512,  128);
    transpose_to_bf16<<<dim3(128/32,  512/32), 256, 0, stream>>>(dec_w[0], wt0,  128,  512);
    transpose_to_bf16<<<dim3(512/32, 1024/32), 256, 0, stream>>>(dec_w[1], wt1,  512, 1024);
    transpose_to_bf16<<<dim3(1024/32,2048/32), 256, 0, stream>>>(dec_w[2], wt2, 1024, 2048);
    transpose_to_bf16<<<dim3(2048/32, 768/32), 256, 0, stream>>>(dec_w[3], wt3, 2048,  768);

    const int nc = B / R;
    const int nRq = B / 16;
    const int rqPerChunk = R / 16;
    const int nvqPerChunk = (R * 128) / 256;
    for (int c = 0; c < nc; c++) {
        const size_t base = (size_t)c * R;
        const float* xc = x + base * 768;
        float* outc = out + base * 768;
        float* idxc = out_idx + base * 4;

        {
            size_t n4 = (size_t)R * 768 / 4;
            split_plane2v_kernel<<<(unsigned)((n4 + 255) / 256), 256, 0, stream>>>(
                (const float4*)xc, xH, xM, n4);
        }

        // encoder (2-plane fp16 MFMA, fp32-grade), remapped grid
        gemm_mfma_split2<true , 1><<<dim3(R/128, 16), 256, 0, stream>>>(
            xH, xM, e0h, e0m, enc_b[0], h0H, h0M, R, 2048, 768);
        gemm_mfma_split2<true , 1><<<dim3(R/128,  8), 256, 0, stream>>>(
            h0H, h0M, e1h, e1m, enc_b[1], h1H, h1M, R, 1024, 2048);
        gemm_mfma_split2<true , 1><<<dim3(R/128,  4), 256, 0, stream>>>(
            h1H, h1M, e2h, e2m, enc_b[2], h2H, h2M, R,  512, 1024);
        gemm_mfma_split2<false, 0><<<dim3(R/128,  1), 256, 0, stream>>>(
            h2H, h2M, e3h, e3m, enc_b[3], zb, nullptr, R, 128, 512);

        // kuma + RQ + inverse + losses (fp32 index path; fast zq path)
        kuma_h_kernel<<<(R * 128) / 256, 256, 0, stream>>>(zb, kp, zpb, R * 128);
        rq_kernel4<<<rqPerChunk, 64, 0, stream>>>(zpb, cb, cbT, cnorm, xqb, idxc,
                                                  prq, c * rqPerChunk, nRq);
        zq_nvq_kernel<<<nvqPerChunk, 256, 0, stream>>>(xqb, zpb, zb, kp, xqb, zq16,
                                                       pnvq, c * nvqPerChunk, R * 128);

        // decoder (bf16 MFMA), remapped grid
        gemm_mfma_bt<true , true ><<<dim3(R/128,  4), 256, 0, stream>>>(zq16, wt0, dec_b[0], dA, R,  512,  128);
        gemm_mfma_bt<true , true ><<<dim3(R/128,  8), 256, 0, stream>>>(dA,   wt1, dec_b[1], dB, R, 1024,  512);
        gemm_mfma_bt<true , true ><<<dim3(R/128, 16), 256, 0, stream>>>(dB,   wt2, dec_b[2], dC, R, 2048, 1024);
        gemm_mfma_bt<false, false><<<dim3(R/128,  6), 256, 0, stream>>>(dC,   wt3, dec_b[3], outc, R,  768, 2048);
    }

    finalize_kernel<<<1, 256, 0, stream>>>(prq, pnvq, 4 * nRq, B * 128 / 256, out_loss);
}

// Round 19
// 874.614 us; speedup vs baseline: 1.0088x; 1.0088x over previous
//
#include <hip/hip_runtime.h>
#include <math.h>

#define EPS_F 1e-6f
#define ONE_M_EPS (1.0f - 1e-6f)

typedef __attribute__((ext_vector_type(8))) short s16x8;
typedef __attribute__((ext_vector_type(8))) _Float16 f16x8;
typedef __attribute__((ext_vector_type(4))) float f32x4;

__device__ __forceinline__ ushort f2bf(float f) {
    union { float f; unsigned u; } v; v.f = f;
    unsigned u = v.u;
    return (ushort)((u + 0x7FFFu + ((u >> 16) & 1u)) >> 16);
}
__device__ __forceinline__ float bf2f(ushort h) {
    union { unsigned u; float f; } v; v.u = ((unsigned)h) << 16;
    return v.f;
}
// fp16 2-plane split: x = h + m, |x - h - m| <= 2^-22 |x|
__device__ __forceinline__ void split2h(float x, ushort& h, ushort& m) {
    union { _Float16 f; ushort u; } a, b;
    a.f = (_Float16)x;
    float r = x - (float)a.f;
    b.f = (_Float16)r;
    h = a.u; m = b.u;
}

#define GLL16(srcp, dstp)                                                     \
    __builtin_amdgcn_global_load_lds(                                         \
        (const __attribute__((address_space(1))) void*)(srcp),                \
        (__attribute__((address_space(3))) void*)(dstp), 16, 0, 0)

// Bank-conflict swizzle (16B-chunk granularity; source+read, LDS linear)
__device__ __forceinline__ int swz_k(int row, int k) { return k ^ ((row >> 1) & 3); }

// Block remap: XCD chunking (bijective, nwg%8==0) + 2x2 supertile clustering
__device__ __forceinline__ void tile_remap(int MB, int NB, int& bm_i, int& bn_i) {
    const int lin = blockIdx.y * MB + blockIdx.x;
    const int nwg = MB * NB;
    int wg = lin;
    if ((nwg & 7) == 0)
        wg = (lin & 7) * (nwg >> 3) + (lin >> 3);
    if (((MB | NB) & 1) == 0) {
        const int tiles_m = MB >> 1;
        const int stile = wg >> 2, within = wg & 3;
        const int st_m = stile % tiles_m, st_n = stile / tiles_m;
        bm_i = st_m * 2 + (within & 1);
        bn_i = st_n * 2 + (within >> 1);
    } else {
        bm_i = wg % MB;
        bn_i = wg / MB;
    }
}

// ---------------------------------------------------------------------------
// 2-plane fp16 MFMA GEMM (encoder): 3 products (hh,hm,mh), fp32 acc.
// 2-phase double-buffered pipeline, counted vmcnt(8), remapped blocks.
// ---------------------------------------------------------------------------
template<bool RELU, int OUT2>
__global__ __launch_bounds__(256) void gemm_mfma_split2(
    const ushort* __restrict__ Ah, const ushort* __restrict__ Am,
    const ushort* __restrict__ Wh, const ushort* __restrict__ Wm,
    const float* __restrict__ bias,
    void* __restrict__ C0, void* __restrict__ C1,
    int M, int N, int K)
{
    __shared__ __align__(16) ushort As[2][2][128 * 32];   // [dbuf][plane]
    __shared__ __align__(16) ushort Bs[2][2][128 * 32];

    const int tid  = threadIdx.x;
    const int lane = tid & 63;
    const int w    = tid >> 6;
    const int wm   = (w >> 1) * 64;
    const int wn   = (w & 1) * 64;
    int bmi, bni;
    tile_remap(gridDim.x, gridDim.y, bmi, bni);
    const int bm   = bmi * 128;
    const int bn   = bni * 128;

    f32x4 acc[4][4];
#pragma unroll
    for (int i = 0; i < 4; i++)
#pragma unroll
        for (int j = 0; j < 4; j++) acc[i][j] = f32x4{0.f, 0.f, 0.f, 0.f};

    const int c0 = (w * 2) * 64 + lane;
    const int c1 = (w * 2 + 1) * 64 + lane;
    const int r0 = c0 >> 2, k0e = swz_k(r0, c0 & 3) * 8;
    const int r1 = c1 >> 2, k1e = swz_k(r1, c1 & 3) * 8;

    const size_t a_off0 = (size_t)(bm + r0) * K + k0e;
    const size_t a_off1 = (size_t)(bm + r1) * K + k1e;
    const size_t b_off0 = (size_t)(bn + r0) * K + k0e;
    const size_t b_off1 = (size_t)(bn + r1) * K + k1e;
    const int d0 = (w * 2) * 512;
    const int d1 = d0 + 512;

    const ushort* Ap[2] = {Ah, Am};
    const ushort* Wp[2] = {Wh, Wm};

    const int fm  = lane & 15;
    const int fkb = lane >> 4;
    const int NT  = K >> 5;

    // prologue: stage tile 0 -> buf 0
#pragma unroll
    for (int p = 0; p < 2; p++) {
        GLL16(Ap[p] + a_off0, &As[0][p][d0]);
        GLL16(Ap[p] + a_off1, &As[0][p][d1]);
        GLL16(Wp[p] + b_off0, &Bs[0][p][d0]);
        GLL16(Wp[p] + b_off1, &Bs[0][p][d1]);
    }

    int cur = 0;
    for (int kt = 0; kt < NT; kt++) {
        if (kt + 1 < NT) {
            const int kk = (kt + 1) << 5;
#pragma unroll
            for (int p = 0; p < 2; p++) {
                GLL16(Ap[p] + a_off0 + kk, &As[cur ^ 1][p][d0]);
                GLL16(Ap[p] + a_off1 + kk, &As[cur ^ 1][p][d1]);
                GLL16(Wp[p] + b_off0 + kk, &Bs[cur ^ 1][p][d0]);
                GLL16(Wp[p] + b_off1 + kk, &Bs[cur ^ 1][p][d1]);
            }
            asm volatile("s_waitcnt vmcnt(8)" ::: "memory");  // tile t complete
        } else {
            asm volatile("s_waitcnt vmcnt(0)" ::: "memory");
        }
        __builtin_amdgcn_s_barrier();
        asm volatile("" ::: "memory");

        f16x8 af[2][4];
#pragma unroll
        for (int p = 0; p < 2; p++)
#pragma unroll
            for (int i = 0; i < 4; i++) {
                const int row = wm + i * 16 + fm;
                af[p][i] = *reinterpret_cast<const f16x8*>(
                    &As[cur][p][row * 32 + swz_k(row, fkb) * 8]);
            }
        f16x8 bf0[4], bf1[4];
#pragma unroll
        for (int j = 0; j < 4; j++) {
            const int row = wn + j * 16 + fm;
            bf0[j] = *reinterpret_cast<const f16x8*>(&Bs[cur][0][row * 32 + swz_k(row, fkb) * 8]);
            bf1[j] = *reinterpret_cast<const f16x8*>(&Bs[cur][1][row * 32 + swz_k(row, fkb) * 8]);
        }

        __builtin_amdgcn_s_setprio(1);
#pragma unroll
        for (int i = 0; i < 4; i++)
#pragma unroll
            for (int j = 0; j < 4; j++) {
                acc[i][j] = __builtin_amdgcn_mfma_f32_16x16x32_f16(af[0][i], bf0[j], acc[i][j], 0, 0, 0);
                acc[i][j] = __builtin_amdgcn_mfma_f32_16x16x32_f16(af[0][i], bf1[j], acc[i][j], 0, 0, 0);
                acc[i][j] = __builtin_amdgcn_mfma_f32_16x16x32_f16(af[1][i], bf0[j], acc[i][j], 0, 0, 0);
            }
        __builtin_amdgcn_s_setprio(0);
        asm volatile("" ::: "memory");
        __builtin_amdgcn_s_barrier();   // reads of buf[cur] done before t+1 overwrites it
        cur ^= 1;
    }

#pragma unroll
    for (int j = 0; j < 4; j++) {
        const int coln = bn + wn + j * 16 + fm;
        const float bv = bias[coln];
#pragma unroll
        for (int i = 0; i < 4; i++) {
            const int row0 = bm + wm + i * 16 + (lane >> 4) * 4;
#pragma unroll
            for (int r = 0; r < 4; r++) {
                float o = acc[i][j][r] + bv;
                if (RELU) o = fmaxf(o, 0.f);
                const size_t idx = (size_t)(row0 + r) * N + coln;
                if (OUT2) {
                    ushort h, m;
                    split2h(o, h, m);
                    ((ushort*)C0)[idx] = h;
                    ((ushort*)C1)[idx] = m;
                } else {
                    ((float*)C0)[idx] = o;
                }
            }
        }
    }
}

// ---------------------------------------------------------------------------
// MFMA bf16 GEMM (decoder, single product), 2-phase pipelined, remapped
// ---------------------------------------------------------------------------
template<bool RELU, bool OUT_BF16>
__global__ __launch_bounds__(256) void gemm_mfma_bt(
    const ushort* __restrict__ A, const ushort* __restrict__ WT,
    const float* __restrict__ bias, void* __restrict__ Cv,
    int M, int N, int K)
{
    __shared__ __align__(16) ushort As[2][128 * 32];
    __shared__ __align__(16) ushort Bs[2][128 * 32];

    const int tid  = threadIdx.x;
    const int lane = tid & 63;
    const int w    = tid >> 6;
    const int wm   = (w >> 1) * 64;
    const int wn   = (w & 1) * 64;
    int bmi, bni;
    tile_remap(gridDim.x, gridDim.y, bmi, bni);
    const int bm   = bmi * 128;
    const int bn   = bni * 128;

    f32x4 acc[4][4];
#pragma unroll
    for (int i = 0; i < 4; i++)
#pragma unroll
        for (int j = 0; j < 4; j++) acc[i][j] = f32x4{0.f, 0.f, 0.f, 0.f};

    const int c0 = (w * 2) * 64 + lane;
    const int c1 = (w * 2 + 1) * 64 + lane;
    const int r0 = c0 >> 2, k0e = swz_k(r0, c0 & 3) * 8;
    const int r1 = c1 >> 2, k1e = swz_k(r1, c1 & 3) * 8;

    const ushort* a_src0 = A  + (size_t)(bm + r0) * K + k0e;
    const ushort* a_src1 = A  + (size_t)(bm + r1) * K + k1e;
    const ushort* b_src0 = WT + (size_t)(bn + r0) * K + k0e;
    const ushort* b_src1 = WT + (size_t)(bn + r1) * K + k1e;
    const int d0 = (w * 2) * 512;
    const int d1 = d0 + 512;

    const int fm  = lane & 15;
    const int fkb = lane >> 4;
    const int NT  = K >> 5;

    GLL16(a_src0, &As[0][d0]);
    GLL16(a_src1, &As[0][d1]);
    GLL16(b_src0, &Bs[0][d0]);
    GLL16(b_src1, &Bs[0][d1]);

    int cur = 0;
    for (int kt = 0; kt < NT; kt++) {
        if (kt + 1 < NT) {
            const int kk = (kt + 1) << 5;
            GLL16(a_src0 + kk, &As[cur ^ 1][d0]);
            GLL16(a_src1 + kk, &As[cur ^ 1][d1]);
            GLL16(b_src0 + kk, &Bs[cur ^ 1][d0]);
            GLL16(b_src1 + kk, &Bs[cur ^ 1][d1]);
            asm volatile("s_waitcnt vmcnt(4)" ::: "memory");
        } else {
            asm volatile("s_waitcnt vmcnt(0)" ::: "memory");
        }
        __builtin_amdgcn_s_barrier();
        asm volatile("" ::: "memory");

        s16x8 af[4], bfr[4];
#pragma unroll
        for (int i = 0; i < 4; i++) {
            const int row = wm + i * 16 + fm;
            af[i] = *reinterpret_cast<const s16x8*>(&As[cur][row * 32 + swz_k(row, fkb) * 8]);
        }
#pragma unroll
        for (int j = 0; j < 4; j++) {
            const int row = wn + j * 16 + fm;
            bfr[j] = *reinterpret_cast<const s16x8*>(&Bs[cur][row * 32 + swz_k(row, fkb) * 8]);
        }

        __builtin_amdgcn_s_setprio(1);
#pragma unroll
        for (int i = 0; i < 4; i++)
#pragma unroll
            for (int j = 0; j < 4; j++)
                acc[i][j] = __builtin_amdgcn_mfma_f32_16x16x32_bf16(
                    af[i], bfr[j], acc[i][j], 0, 0, 0);
        __builtin_amdgcn_s_setprio(0);
        asm volatile("" ::: "memory");
        __builtin_amdgcn_s_barrier();
        cur ^= 1;
    }

#pragma unroll
    for (int j = 0; j < 4; j++) {
        const int coln = bn + wn + j * 16 + fm;
        const float bv = bias[coln];
#pragma unroll
        for (int i = 0; i < 4; i++) {
            const int row0 = bm + wm + i * 16 + (lane >> 4) * 4;
#pragma unroll
            for (int r = 0; r < 4; r++) {
                float o = acc[i][j][r] + bv;
                if (RELU) o = fmaxf(o, 0.f);
                if (OUT_BF16)
                    ((ushort*)Cv)[(size_t)(row0 + r) * N + coln] = f2bf(o);
                else
                    ((float*)Cv)[(size_t)(row0 + r) * N + coln] = o;
            }
        }
    }
}

// ---------------------------------------------------------------------------
// Weight prep kernels
// ---------------------------------------------------------------------------
__global__ __launch_bounds__(256) void transpose_to_bf16(
    const float* __restrict__ W, ushort* __restrict__ WT, int K, int N)
{
    __shared__ float t[32][33];
    const int kb = blockIdx.x * 32, nb = blockIdx.y * 32;
    const int tx = threadIdx.x & 31, ty = threadIdx.x >> 5;
#pragma unroll
    for (int i = ty; i < 32; i += 8)
        t[i][tx] = W[(size_t)(kb + i) * N + nb + tx];
    __syncthreads();
#pragma unroll
    for (int i = ty; i < 32; i += 8)
        WT[(size_t)(nb + i) * K + kb + tx] = f2bf(t[tx][i]);
}

__global__ __launch_bounds__(256) void transpose_split_f16(
    const float* __restrict__ W, ushort* __restrict__ TH,
    ushort* __restrict__ TM, int K, int N)
{
    __shared__ float t[32][33];
    const int kb = blockIdx.x * 32, nb = blockIdx.y * 32;
    const int tx = threadIdx.x & 31, ty = threadIdx.x >> 5;
#pragma unroll
    for (int i = ty; i < 32; i += 8)
        t[i][tx] = W[(size_t)(kb + i) * N + nb + tx];
    __syncthreads();
#pragma unroll
    for (int i = ty; i < 32; i += 8) {
        ushort h, m;
        split2h(t[tx][i], h, m);
        const size_t idx = (size_t)(nb + i) * K + kb + tx;
        TH[idx] = h; TM[idx] = m;
    }
}

__global__ __launch_bounds__(256) void split_plane2_kernel(
    const float* __restrict__ X, ushort* __restrict__ H,
    ushort* __restrict__ M, size_t n)
{
    size_t i = (size_t)blockIdx.x * 256 + threadIdx.x;
    if (i >= n) return;
    ushort h, m;
    split2h(X[i], h, m);
    H[i] = h; M[i] = m;
}

// ---------------------------------------------------------------------------
// Codebook prep
// ---------------------------------------------------------------------------
__global__ __launch_bounds__(128) void prep_cb_kernel(
    const float* __restrict__ cb, float* __restrict__ cbT, float* __restrict__ cnorm)
{
    int b = blockIdx.x;
    int d = threadIdx.x;
    float v = cb[(size_t)b * 128 + d];
    int l = b >> 8, c = b & 255;
    cbT[((size_t)l * 128 + d) * 256 + c] = v;
    float s = v * v;
#pragma unroll
    for (int off = 32; off > 0; off >>= 1) s += __shfl_down(s, off);
    __shared__ float ps[2];
    if ((d & 63) == 0) ps[d >> 6] = s;
    __syncthreads();
    if (d == 0) cnorm[b] = ps[0] + ps[1];
}

__device__ __forceinline__ float softplusf(float x) {
    return (x > 20.f) ? x : log1pf(expf(x));
}

__global__ void kuma_ab_init(const float* __restrict__ a_raw, const float* __restrict__ b_raw,
                             float* __restrict__ kp)
{
    int t = threadIdx.x;
    if (t < 128) {
        float a = softplusf(a_raw[t]) + EPS_F;
        float b = softplusf(b_raw[t]) + EPS_F;
        kp[t] = a;
        kp[128 + t] = b;
        kp[256 + t] = 1.f / a;
        kp[384 + t] = 1.f / b;
    }
}

__global__ __launch_bounds__(256) void kuma_h_kernel(
    const float* __restrict__ z, const float* __restrict__ kp,
    float* __restrict__ zp, int n)
{
    int i = blockIdx.x * 256 + threadIdx.x;
    if (i >= n) return;
    int col = i & 127;
    float a = kp[col], b = kp[128 + col];
    float zv = z[i];
    float x = 1.f / (1.f + expf(-zv));
    x = fminf(fmaxf(x, EPS_F), ONE_M_EPS);
    float inner = 1.f - powf(x, a);
    inner = fminf(fmaxf(inner, EPS_F), 1.f);
    float y = 1.f - powf(inner, b);
    y = fminf(fmaxf(y, EPS_F), ONE_M_EPS);
    zp[i] = y;
}

// ---------------------------------------------------------------------------
// Residual quantizer v3 — 1 wave/block, 8 rows, 4 codes/thread.
// ---------------------------------------------------------------------------
__global__ __launch_bounds__(64) void rq_kernel3(
    const float* __restrict__ zp, const float* __restrict__ cb,
    const float* __restrict__ cbT, const float* __restrict__ cnorm,
    float* __restrict__ xq, float* __restrict__ idx_out,
    float* __restrict__ prq, int bid0, int nRq)
{
    __shared__ float res[8][128];

    const int t = threadIdx.x;
    const int row0 = blockIdx.x * 8;

#pragma unroll
    for (int j = 0; j < 16; j++) {
        int e = t + j * 64;
        res[e >> 7][e & 127] = zp[(size_t)row0 * 128 + e];
    }

    float lsum[4];
    int bidx[8];

#pragma unroll 1
    for (int l = 0; l < 4; l++) {
        const float* cT = cbT + (size_t)l * 32768;

        float acc[8][4];
#pragma unroll
        for (int r = 0; r < 8; r++)
#pragma unroll
            for (int cc = 0; cc < 4; cc++) acc[r][cc] = 0.f;

        float pc[16];
#pragma unroll
        for (int dd = 0; dd < 4; dd++)
#pragma unroll
            for (int cc = 0; cc < 4; cc++)
                pc[dd * 4 + cc] = cT[dd * 256 + cc * 64 + t];

#pragma unroll 2
        for (int d = 0; d < 128; d += 4) {
            float nc[16];
            if (d < 124) {
#pragma unroll
                for (int dd = 0; dd < 4; dd++)
#pragma unroll
                    for (int cc = 0; cc < 4; cc++)
                        nc[dd * 4 + cc] = cT[(d + 4 + dd) * 256 + cc * 64 + t];
            }
#pragma unroll
            for (int r = 0; r < 8; r++) {
                float4 rv = *reinterpret_cast<const float4*>(&res[r][d]);
#pragma unroll
                for (int cc = 0; cc < 4; cc++) {
                    acc[r][cc] += rv.x * pc[cc] + rv.y * pc[4 + cc]
                                + rv.z * pc[8 + cc] + rv.w * pc[12 + cc];
                }
            }
#pragma unroll
            for (int k = 0; k < 16; k++) pc[k] = nc[k];
        }

        float cn[4];
#pragma unroll
        for (int cc = 0; cc < 4; cc++) cn[cc] = cnorm[l * 256 + cc * 64 + t];

#pragma unroll
        for (int r = 0; r < 8; r++) {
            float dmin = cn[0] - 2.f * acc[r][0];
            int imin = t;
#pragma unroll
            for (int cc = 1; cc < 4; cc++) {
                float dv = cn[cc] - 2.f * acc[r][cc];
                if (dv < dmin) { dmin = dv; imin = cc * 64 + t; }
            }
#pragma unroll
            for (int off = 1; off < 64; off <<= 1) {
                float d2 = __shfl_xor(dmin, off);
                int i2 = __shfl_xor(imin, off);
                if (d2 < dmin || (d2 == dmin && i2 < imin)) { dmin = d2; imin = i2; }
            }
            bidx[r] = imin;
            if (t == 0) idx_out[(size_t)(row0 + r) * 4 + l] = (float)imin;
        }

        float s = 0.f;
#pragma unroll
        for (int j = 0; j < 16; j++) {
            const int r = j >> 1;
            const int d = (j & 1) * 64 + t;
            float q = cb[((size_t)(l * 256) + bidx[r]) * 128 + d];
            float nr = res[r][d] - q;
            res[r][d] = nr;
            s += nr * nr;
        }
        lsum[l] = s;
    }

#pragma unroll
    for (int j = 0; j < 16; j++) {
        int e = t + j * 64;
        xq[(size_t)row0 * 128 + e] = zp[(size_t)row0 * 128 + e] - res[e >> 7][e & 127];
    }

#pragma unroll
    for (int l = 0; l < 4; l++) {
        float s = lsum[l];
#pragma unroll
        for (int off = 32; off > 0; off >>= 1) s += __shfl_down(s, off);
        if (t == 0) prq[(size_t)l * nRq + bid0 + blockIdx.x] = s;
    }
}

// ---------------------------------------------------------------------------
// z_q = h_inv(x_q) (+ bf16 copy);  z_recon = h_inv(z');  nvq partial store
// ---------------------------------------------------------------------------
__device__ __forceinline__ float kuma_h_inv_f(float y, float ia, float ib) {
    y = fminf(fmaxf(y, EPS_F), ONE_M_EPS);
    float omy = fminf(fmaxf(1.f - y, EPS_F), 1.f);
    float inner = fminf(fmaxf(1.f - powf(omy, ib), EPS_F), ONE_M_EPS);
    float x = fminf(fmaxf(powf(inner, ia), EPS_F), ONE_M_EPS);
    return logf(x / (1.f - x));
}

__global__ __launch_bounds__(256) void zq_nvq_kernel(
    const float* __restrict__ xq, const float* __restrict__ zp,
    const float* __restrict__ z, const float* __restrict__ kp,
    float* __restrict__ zq, ushort* __restrict__ zq16,
    float* __restrict__ pnvq, int bid0, int n)
{
    int i = blockIdx.x * 256 + threadIdx.x;
    float ds = 0.f;
    if (i < n) {
        int col = i & 127;
        float ia = kp[256 + col], ib = kp[384 + col];
        float xv = xq[i];
        float zpv = zp[i];
        float zv = z[i];
        float zr = kuma_h_inv_f(zpv, ia, ib);
        float d = zr - zv;
        ds = d * d;
        float zqv = kuma_h_inv_f(xv, ia, ib);
        zq[i] = zqv;
        zq16[i] = f2bf(zqv);
    }
#pragma unroll
    for (int off = 32; off > 0; off >>= 1) ds += __shfl_down(ds, off);
    __shared__ float ps[4];
    if ((threadIdx.x & 63) == 0) ps[threadIdx.x >> 6] = ds;
    __syncthreads();
    if (threadIdx.x == 0)
        pnvq[bid0 + blockIdx.x] = ps[0] + ps[1] + ps[2] + ps[3];
}

// ---------------------------------------------------------------------------
// Final loss
// ---------------------------------------------------------------------------
__global__ __launch_bounds__(256) void finalize_kernel(
    const float* __restrict__ prq, const float* __restrict__ pnvq,
    int nRqAll, int nNvq, float* __restrict__ out_loss)
{
    const int t = threadIdx.x;
    float srq = 0.f, snvq = 0.f;
    for (int i = t; i < nRqAll; i += 256) srq += prq[i];
    for (int i = t; i < nNvq; i += 256) snvq += pnvq[i];
#pragma unroll
    for (int off = 32; off > 0; off >>= 1) {
        srq += __shfl_down(srq, off);
        snvq += __shfl_down(snvq, off);
    }
    __shared__ float pr[4], pn[4];
    if ((t & 63) == 0) { pr[t >> 6] = srq; pn[t >> 6] = snvq; }
    __syncthreads();
    if (t == 0) {
        const float inv = 1.f / (16384.f * 128.f);
        float rq = (pr[0] + pr[1] + pr[2] + pr[3]);
        float nv = (pn[0] + pn[1] + pn[2] + pn[3]);
        out_loss[0] = 0.3125f * rq * inv + nv * inv;
    }
}

// ---------------------------------------------------------------------------
// Launcher — fp16 2-plane pipelined MFMA encoder + bf16 pipelined decoder.
// ---------------------------------------------------------------------------
extern "C" void kernel_launch(void* const* d_in, const int* in_sizes, int n_in,
                              void* d_out, int out_size, void* d_ws, size_t ws_size,
                              hipStream_t stream)
{
    constexpr int B = 16384;

    const float* x = (const float*)d_in[0];
    const float* enc_w[4]; const float* enc_b[4];
    const float* dec_w[4]; const float* dec_b[4];
    for (int i = 0; i < 4; i++) {
        enc_w[i] = (const float*)d_in[1 + 4 * i];
        enc_b[i] = (const float*)d_in[2 + 4 * i];
        dec_w[i] = (const float*)d_in[3 + 4 * i];
        dec_b[i] = (const float*)d_in[4 + 4 * i];
    }
    const float* cb    = (const float*)d_in[17];
    const float* a_raw = (const float*)d_in[18];
    const float* b_raw = (const float*)d_in[19];

    // chunk size
    size_t avail = ws_size / 4;
    const size_t fixed_f = 6547008;
    int R = 16384;
    while (R > 256 && (size_t)R * 3520 + fixed_f > avail) R >>= 1;

    // carve (floats)
    float* ws    = (float*)d_ws;
    float* slotA = ws;                         // R*1024 fl
    float* slotB = slotA + (size_t)R * 1024;   // R*2048 fl
    float* zb    = slotB + (size_t)R * 2048;   // R*128
    float* zpb   = zb  + (size_t)R * 128;      // R*128
    float* xqb   = zpb + (size_t)R * 128;      // R*128
    float* zq16f = xqb + (size_t)R * 128;      // R*64 (ushort R*128)
    float* fixp  = zq16f + (size_t)R * 64;

    ushort* ew = (ushort*)fixp;
    ushort* e0h = ew;            ushort* e0m = e0h + 1572864;
    ushort* e1h = e0m + 1572864; ushort* e1m = e1h + 2097152;
    ushort* e2h = e1m + 2097152; ushort* e2m = e2h + 524288;
    ushort* e3h = e2m + 524288;  ushort* e3m = e3h + 65536;
    ushort* wt0 = e3m + 65536;
    ushort* wt1 = wt0 + 65536;
    ushort* wt2 = wt1 + 524288;
    ushort* wt3 = wt2 + 2097152;
    float* cbT   = (float*)(wt3 + 1572864);
    float* cnorm = cbT + 4 * 128 * 256;
    float* kp    = cnorm + 4 * 256;
    float* prq   = kp + 512;              // 4 * (B/8) = 8192
    float* pnvq  = prq + 16384;           // 8192

    ushort* zq16 = (ushort*)zq16f;

    ushort* xH  = (ushort*)slotA;  ushort* xM  = xH  + (size_t)R * 768;
    ushort* h0H = (ushort*)slotB;  ushort* h0M = h0H + (size_t)R * 2048;
    ushort* h1H = (ushort*)slotA;  ushort* h1M = h1H + (size_t)R * 1024;
    ushort* h2H = (ushort*)slotB;  ushort* h2M = h2H + (size_t)R * 512;

    ushort* dA = (ushort*)slotB;
    ushort* dB = (ushort*)(slotB + (size_t)R * 256);
    ushort* dC = (ushort*)slotA;

    float* out      = (float*)d_out;
    float* out_loss = out + (size_t)B * 768;
    float* out_idx  = out_loss + 1;

    // prep (once per launch)
    prep_cb_kernel<<<1024, 128, 0, stream>>>(cb, cbT, cnorm);
    kuma_ab_init<<<1, 128, 0, stream>>>(a_raw, b_raw, kp);
    transpose_split_f16<<<dim3( 768/32, 2048/32), 256, 0, stream>>>(enc_w[0], e0h, e0m,  768, 2048);
    transpose_split_f16<<<dim3(2048/32, 1024/32), 256, 0, stream>>>(enc_w[1], e1h, e1m, 2048, 1024);
    transpose_split_f16<<<dim3(1024/32,  512/32), 256, 0, stream>>>(enc_w[2], e2h, e2m, 1024,  512);
    transpose_split_f16<<<dim3( 512/32,  128/32), 256, 0, stream>>>(enc_w[3], e3h, e3m,  512,  128);
    transpose_to_bf16<<<dim3(128/32,  512/32), 256, 0, stream>>>(dec_w[0], wt0,  128,  512);
    transpose_to_bf16<<<dim3(512/32, 1024/32), 256, 0, stream>>>(dec_w[1], wt1,  512, 1024);
    transpose_to_bf16<<<dim3(1024/32,2048/32), 256, 0, stream>>>(dec_w[2], wt2, 1024, 2048);
    transpose_to_bf16<<<dim3(2048/32, 768/32), 256, 0, stream>>>(dec_w[3], wt3, 2048,  768);

    const int nc = B / R;
    const int nRq = B / 8;
    const int rqPerChunk = R / 8;
    const int nvqPerChunk = (R * 128) / 256;
    for (int c = 0; c < nc; c++) {
        const size_t base = (size_t)c * R;
        const float* xc = x + base * 768;
        float* outc = out + base * 768;
        float* idxc = out_idx + base * 4;

        {
            size_t n = (size_t)R * 768;
            split_plane2_kernel<<<(unsigned)((n + 255) / 256), 256, 0, stream>>>(xc, xH, xM, n);
        }

        // encoder (2-plane fp16 MFMA, fp32-grade), remapped grid
        gemm_mfma_split2<true , 1><<<dim3(R/128, 16), 256, 0, stream>>>(
            xH, xM, e0h, e0m, enc_b[0], h0H, h0M, R, 2048, 768);
        gemm_mfma_split2<true , 1><<<dim3(R/128,  8), 256, 0, stream>>>(
            h0H, h0M, e1h, e1m, enc_b[1], h1H, h1M, R, 1024, 2048);
        gemm_mfma_split2<true , 1><<<dim3(R/128,  4), 256, 0, stream>>>(
            h1H, h1M, e2h, e2m, enc_b[2], h2H, h2M, R,  512, 1024);
        gemm_mfma_split2<false, 0><<<dim3(R/128,  1), 256, 0, stream>>>(
            h2H, h2M, e3h, e3m, enc_b[3], zb, nullptr, R, 128, 512);

        // kuma + RQ + inverse + losses (fp32)
        kuma_h_kernel<<<(R * 128) / 256, 256, 0, stream>>>(zb, kp, zpb, R * 128);
        rq_kernel3<<<rqPerChunk, 64, 0, stream>>>(zpb, cb, cbT, cnorm, xqb, idxc,
                                                  prq, c * rqPerChunk, nRq);
        zq_nvq_kernel<<<nvqPerChunk, 256, 0, stream>>>(xqb, zpb, zb, kp, xqb, zq16,
                                                       pnvq, c * nvqPerChunk, R * 128);

        // decoder (bf16 MFMA), remapped grid
        gemm_mfma_bt<true , true ><<<dim3(R/128,  4), 256, 0, stream>>>(zq16, wt0, dec_b[0], dA, R,  512,  128);
        gemm_mfma_bt<true , true ><<<dim3(R/128,  8), 256, 0, stream>>>(dA,   wt1, dec_b[1], dB, R, 1024,  512);
        gemm_mfma_bt<true , true ><<<dim3(R/128, 16), 256, 0, stream>>>(dB,   wt2, dec_b[2], dC, R, 2048, 1024);
        gemm_mfma_bt<false, false><<<dim3(R/128,  6), 256, 0, stream>>>(dC,   wt3, dec_b[3], outc, R,  768, 2048);
    }

    finalize_kernel<<<1, 256, 0, stream>>>(prq, pnvq, 4 * nRq, B * 128 / 256, out_loss);
}